// Round 15
// baseline (886.443 us; speedup 1.0000x reference)
//
#include <hip/hip_runtime.h>
#include <stdint.h>

// WeightOnlyInt4Linear: y = X @ dequant(Q)^T ; M=8192, K=4096, N=11008, G=128.
// Round 15: r14 (B operand direct global->register, fragment-tiled prepass;
// A-only LDS) with the B column-index bug fixed: nb = nt*16 + wc*4 + nf,
// matching the epilogue c = col0 + wc*64 + nf*16 + l15. (r14 used the old
// column-half mapping -> scrambled columns, absmax 64.)

typedef __attribute__((ext_vector_type(8))) short short8;
typedef __attribute__((ext_vector_type(4))) float float4v;
typedef __attribute__((ext_vector_type(4))) int int4v;
typedef __attribute__((ext_vector_type(2))) float float2v;
typedef __attribute__((ext_vector_type(4))) unsigned short ushort4v;

static constexpr int M_ = 8192;
static constexpr int K_ = 4096;
static constexpr int N_ = 11008;
static constexpr int NKT = K_ / 64;  // 64 K-tiles

__device__ __forceinline__ unsigned short f2bf(float f) {
    union { float f; uint32_t u; } v;
    v.f = f;
    uint32_t u = v.u;
    u += 0x7fffu + ((u >> 16) & 1u);  // RNE
    return (unsigned short)(u >> 16);
}

__device__ __forceinline__ void gload16(const void* g, void* l) {
    __builtin_amdgcn_global_load_lds(
        (const __attribute__((address_space(1))) uint32_t*)g,
        (__attribute__((address_space(3))) uint32_t*)l, 16, 0, 0);
}

// ---------------- Prepass 1: X fp32 -> bf16 ----------------
__global__ __launch_bounds__(256) void cvt_x_kernel(const float* __restrict__ X,
                                                    unsigned short* __restrict__ Xb) {
    const int i = blockIdx.x * 256 + threadIdx.x;
    const float4v a = ((const float4v*)X)[2 * (size_t)i];
    const float4v b = ((const float4v*)X)[2 * (size_t)i + 1];
    short8 o;
    #pragma unroll
    for (int j = 0; j < 4; ++j) o[j] = (short)f2bf(a[j]);
    #pragma unroll
    for (int j = 0; j < 4; ++j) o[4 + j] = (short)f2bf(b[j]);
    ((short8*)Xb)[(size_t)i] = o;
}

// ---------------- Prepass 2: W int4 -> bf16, FRAGMENT-TILED layout ----------
// Wb[nb][kb][lane][j] : n = nb*16 + (lane&15), k = kb*32 + (lane>>4)*8 + j.
// A wave's MFMA B-fragment (nb, kb) = 64 lanes x 16 B contiguous.
__global__ __launch_bounds__(256) void deq_w_kernel(const int* __restrict__ Q,
                                                    const float* __restrict__ SZ,
                                                    unsigned short* __restrict__ Wb) {
    const int i = blockIdx.x * 256 + threadIdx.x;  // < N*K/8 = 5,636,096
    const int lane = i & 63;
    const int rest = i >> 6;
    const int kb = rest & 127;       // K/32 = 128
    const int nb = rest >> 7;        // N/16 = 688
    const int n = nb * 16 + (lane & 15);
    const int k0 = kb * 32 + (lane >> 4) * 8;
    const int g = kb >> 2;           // G=128 -> 4 kb per group
    const float2v sz = *(const float2v*)(SZ + ((size_t)g * N_ + n) * 2);
    const float s = sz[0], z = sz[1];
    const int4v q0 = *(const int4v*)(Q + (size_t)n * K_ + k0);
    const int4v q1 = *(const int4v*)(Q + (size_t)n * K_ + k0 + 4);
    short8 o;
    #pragma unroll
    for (int j = 0; j < 4; ++j) o[j] = (short)f2bf((float)(q0[j] - 8) * s + z);
    #pragma unroll
    for (int j = 0; j < 4; ++j) o[4 + j] = (short)f2bf((float)(q1[j] - 8) * s + z);
    ((short8*)Wb)[(size_t)i] = o;
}

// ---------------- 256x256 GEMM, A-in-LDS + B-in-registers ----------------
// LDS (A only): buf0 [0,32K) buf1 [32K,64K); 256 rows x 64 bf16 (128 B/row).
// Swizzle: phys 16B-slot = logical_slot ^ (row&7).

#define SBAR() __builtin_amdgcn_sched_barrier(0)
#define VMW0() asm volatile("s_waitcnt vmcnt(0)" ::: "memory")
#define LGKM(n) asm volatile("s_waitcnt lgkmcnt(" #n ")" ::: "memory")
#define BARRIER() __builtin_amdgcn_s_barrier()

__global__ __launch_bounds__(512, 2) void gemm_bf16_breg(
    const unsigned short* __restrict__ Agl,  // [M][K] bf16
    const unsigned short* __restrict__ Wt,   // fragment-tiled Wb
    float* __restrict__ C) {
    __shared__ alignas(16) unsigned short lds[32768];  // 64 KiB, A only

    const int tid = threadIdx.x;
    const int lane = tid & 63;
    const int wid = tid >> 6;   // 0..7
    const int wr = wid >> 2;    // 0..1 -> rows wr*128..+127
    const int wc = wid & 3;     // 0..3 -> cols wc*64..+63

    // T1: XCD swizzle over 1376 = 8*172 blocks.
    const int bid = blockIdx.x;
    const int wg = (bid & 7) * 172 + (bid >> 3);
    const int mt = wg / 43;
    const int nt = wg % 43;
    const int row0 = mt * 256;
    const int col0 = nt * 256;

    // staging lane geometry: wave writes 8 rows x 128 B linear.
    const int r8 = lane >> 3;
    const int kc = ((lane & 7) ^ r8) * 8;    // inverse-swizzled k-elem offset

    // A ds_read lane geometry (16x16x32): row = base + l15, slot = ks*4+lg.
    const int l15 = lane & 15;
    const int lg = lane >> 4;
    const int aR0 = (wr * 128 + l15) * 128 + (((lg) ^ (l15 & 7)) << 4);
    const int aR1 = aR0 ^ 64;  // slot bit2 flip = byte bit6; commutes with XOR
    const char* ldsB = (const char*)lds;
    unsigned short* ldsU = lds;
    const char* AglB = (const char*)Agl;
    const char* WtB = (const char*)Wt;

    // A staging streams (4/wave, +128 B per tile).
    uint32_t sa0 = (uint32_t)(row0 + wid * 32 + 0 + r8) * (K_ * 2) + (uint32_t)kc * 2;
    uint32_t sa1 = (uint32_t)(row0 + wid * 32 + 8 + r8) * (K_ * 2) + (uint32_t)kc * 2;
    uint32_t sa2 = (uint32_t)(row0 + wid * 32 + 16 + r8) * (K_ * 2) + (uint32_t)kc * 2;
    uint32_t sa3 = (uint32_t)(row0 + wid * 32 + 24 + r8) * (K_ * 2) + (uint32_t)kc * 2;

    // B fragment streams: frag (nf, ks): nb = nt*16 + wc*4 + nf (FIXED),
    // kb = t*2 + ks; byte = ((nb*128 + kb)*64 + lane)*16 ; += 2048/tile.
#define BOFF(nf, ks) \
    (uint32_t)((((uint32_t)(nt * 16 + wc * 4 + (nf)) * 128 + (ks)) * 64 + lane) * 16)
    uint32_t bo00 = BOFF(0, 0), bo01 = BOFF(0, 1);
    uint32_t bo10 = BOFF(1, 0), bo11 = BOFF(1, 1);
    uint32_t bo20 = BOFF(2, 0), bo21 = BOFF(2, 1);
    uint32_t bo30 = BOFF(3, 0), bo31 = BOFF(3, 1);
#undef BOFF

    float4v acc[8][4] = {};
    short8 aX[2][2];        // A pipeline slots [slot][ks]
    short8 breg[2][4][2];   // B frags [buf][nf][ks] (static indices only)

    auto gAst = [&](int b) {  // stage A tile -> LDS buf b (4 gload16)
        gload16(AglB + sa0, ldsU + b * 16384 + (wid * 32 + 0) * 64); sa0 += 128;
        gload16(AglB + sa1, ldsU + b * 16384 + (wid * 32 + 8) * 64); sa1 += 128;
        gload16(AglB + sa2, ldsU + b * 16384 + (wid * 32 + 16) * 64); sa2 += 128;
        gload16(AglB + sa3, ldsU + b * 16384 + (wid * 32 + 24) * 64); sa3 += 128;
    };

#define LDB(BN)                                                               \
    breg[BN][0][0] = *(const short8*)(WtB + bo00); bo00 += 2048;              \
    breg[BN][0][1] = *(const short8*)(WtB + bo01); bo01 += 2048;              \
    breg[BN][1][0] = *(const short8*)(WtB + bo10); bo10 += 2048;              \
    breg[BN][1][1] = *(const short8*)(WtB + bo11); bo11 += 2048;              \
    breg[BN][2][0] = *(const short8*)(WtB + bo20); bo20 += 2048;              \
    breg[BN][2][1] = *(const short8*)(WtB + bo21); bo21 += 2048;              \
    breg[BN][3][0] = *(const short8*)(WtB + bo30); bo30 += 2048;              \
    breg[BN][3][1] = *(const short8*)(WtB + bo31); bo31 += 2048;

#define RD2(BUF, MF, SLOT)                                                    \
    aX[SLOT][0] = *(const short8*)(ldsB + (BUF) * 32768 + (MF) * 2048 + aR0); \
    aX[SLOT][1] = *(const short8*)(ldsB + (BUF) * 32768 + (MF) * 2048 + aR1);

#define MMA8(MF, SLOT, BUF)                                                   \
    __builtin_amdgcn_s_setprio(1);                                            \
    acc[MF][0] = __builtin_amdgcn_mfma_f32_16x16x32_bf16(aX[SLOT][0], breg[BUF][0][0], acc[MF][0], 0, 0, 0); \
    acc[MF][0] = __builtin_amdgcn_mfma_f32_16x16x32_bf16(aX[SLOT][1], breg[BUF][0][1], acc[MF][0], 0, 0, 0); \
    acc[MF][1] = __builtin_amdgcn_mfma_f32_16x16x32_bf16(aX[SLOT][0], breg[BUF][1][0], acc[MF][1], 0, 0, 0); \
    acc[MF][1] = __builtin_amdgcn_mfma_f32_16x16x32_bf16(aX[SLOT][1], breg[BUF][1][1], acc[MF][1], 0, 0, 0); \
    acc[MF][2] = __builtin_amdgcn_mfma_f32_16x16x32_bf16(aX[SLOT][0], breg[BUF][2][0], acc[MF][2], 0, 0, 0); \
    acc[MF][2] = __builtin_amdgcn_mfma_f32_16x16x32_bf16(aX[SLOT][1], breg[BUF][2][1], acc[MF][2], 0, 0, 0); \
    acc[MF][3] = __builtin_amdgcn_mfma_f32_16x16x32_bf16(aX[SLOT][0], breg[BUF][3][0], acc[MF][3], 0, 0, 0); \
    acc[MF][3] = __builtin_amdgcn_mfma_f32_16x16x32_bf16(aX[SLOT][1], breg[BUF][3][1], acc[MF][3], 0, 0, 0); \
    __builtin_amdgcn_s_setprio(0);

    // Prologue: A(0) -> buf0, B(0) -> breg[0]; drain; barrier.
    gAst(0);
    LDB(0)
    VMW0();
    BARRIER(); SBAR();

    // Per tile t (BUF=t&1): issue B(t+1)->breg[BUF^1] + A-stage(t+1)->buf^1,
    // then 2-deep counted-lgkm A pipeline: 8 chunks of {2 ds_read | 8 MFMA}.
    // End: vmcnt(0) (issued ~2000cy earlier) + barrier.
#define KTILE(BUF, DN)                                                        \
    {                                                                         \
        if (DN) { LDB((BUF) ^ 1) gAst((BUF) ^ 1); }                           \
        RD2(BUF, 0, 0)                                                        \
        RD2(BUF, 1, 1)                                                        \
        LGKM(2); SBAR();                                                      \
        MMA8(0, 0, BUF)                                                       \
        RD2(BUF, 2, 0)                                                        \
        LGKM(2); SBAR();                                                      \
        MMA8(1, 1, BUF)                                                       \
        RD2(BUF, 3, 1)                                                        \
        LGKM(2); SBAR();                                                      \
        MMA8(2, 0, BUF)                                                       \
        RD2(BUF, 4, 0)                                                        \
        LGKM(2); SBAR();                                                      \
        MMA8(3, 1, BUF)                                                       \
        RD2(BUF, 5, 1)                                                        \
        LGKM(2); SBAR();                                                      \
        MMA8(4, 0, BUF)                                                       \
        RD2(BUF, 6, 0)                                                        \
        LGKM(2); SBAR();                                                      \
        MMA8(5, 1, BUF)                                                       \
        RD2(BUF, 7, 1)                                                        \
        LGKM(2); SBAR();                                                      \
        MMA8(6, 0, BUF)                                                       \
        LGKM(0); SBAR();                                                      \
        MMA8(7, 1, BUF)                                                       \
        if (DN) {                                                             \
            VMW0();                                                           \
            BARRIER(); SBAR();                                                \
        }                                                                     \
    }

    for (int t2 = 0; t2 < 62; t2 += 2) {
        KTILE(0, 1);
        KTILE(1, 1);
    }
    KTILE(0, 1);  // t=62: loads t=63 (breg[1], A buf1)
    KTILE(1, 0);  // t=63: pure compute
#undef KTILE
#undef MMA8
#undef RD2
#undef LDB

    // Epilogue: D map col=lane&15, row=(lane>>4)*4+j (m89-verified).
    // Wave tile: rows row0+wr*128..+127 (mf*16), cols col0+wc*64..+63 (nf*16).
    const int lrow = lg * 4;
    #pragma unroll
    for (int mf = 0; mf < 8; ++mf)
        #pragma unroll
        for (int nf = 0; nf < 4; ++nf)
            #pragma unroll
            for (int j = 0; j < 4; ++j) {
                const int r = row0 + wr * 128 + mf * 16 + lrow + j;
                const int c = col0 + wc * 64 + nf * 16 + l15;
                C[(size_t)r * N_ + c] = acc[mf][nf][j];
            }
}

// ---------------- Fallback: round-1 fused kernel ----------------
static constexpr int LDSS = 40;

__global__ __launch_bounds__(256, 2) void w4_gemm_fused(
    const float* __restrict__ X, const int* __restrict__ Q,
    const float* __restrict__ SZ, float* __restrict__ C) {
    __shared__ alignas(16) unsigned short As[128 * LDSS];
    __shared__ alignas(16) unsigned short Ws[128 * LDSS];
    const int tid = threadIdx.x;
    const int lane = tid & 63;
    const int wid = tid >> 6;
    const int wrr = wid >> 1;
    const int wcc = wid & 1;
    const int row0 = blockIdx.x * 128;
    const int col0 = blockIdx.y * 128;
    float4v acc[4][4] = {};
    float4v a_reg[4];
    int4v q_reg[4];
    float2v sz_reg[4];

    auto load_tile = [&](int kb) {
        const int g = kb >> 7;
        #pragma unroll
        for (int i = 0; i < 4; ++i) {
            const int idx = tid + 256 * i;
            const int r = idx >> 3;
            const int v = idx & 7;
            a_reg[i] = *(const float4v*)(X + (size_t)(row0 + r) * K_ + kb + v * 4);
            q_reg[i] = *(const int4v*)(Q + (size_t)(col0 + r) * K_ + kb + v * 4);
            sz_reg[i] = *(const float2v*)(SZ + ((size_t)g * N_ + (col0 + r)) * 2);
        }
    };
    auto write_tile = [&]() {
        #pragma unroll
        for (int i = 0; i < 4; ++i) {
            const int idx = tid + 256 * i;
            const int r = idx >> 3;
            const int v = idx & 7;
            ushort4v ab, wb;
            #pragma unroll
            for (int j = 0; j < 4; ++j) ab[j] = f2bf(a_reg[i][j]);
            const float s = sz_reg[i][0];
            const float z = sz_reg[i][1];
            #pragma unroll
            for (int j = 0; j < 4; ++j) wb[j] = f2bf((float)(q_reg[i][j] - 8) * s + z);
            *(ushort4v*)(&As[r * LDSS + v * 4]) = ab;
            *(ushort4v*)(&Ws[r * LDSS + v * 4]) = wb;
        }
    };
    auto compute = [&]() {
        const int lr = lane & 15;
        const int lgg = lane >> 4;
        short8 af[4], bf[4];
        #pragma unroll
        for (int mf = 0; mf < 4; ++mf)
            af[mf] = *(const short8*)(&As[(wrr * 64 + mf * 16 + lr) * LDSS + lgg * 8]);
        #pragma unroll
        for (int nf = 0; nf < 4; ++nf)
            bf[nf] = *(const short8*)(&Ws[(wcc * 64 + nf * 16 + lr) * LDSS + lgg * 8]);
        #pragma unroll
        for (int mf = 0; mf < 4; ++mf)
            #pragma unroll
            for (int nf = 0; nf < 4; ++nf)
                acc[mf][nf] = __builtin_amdgcn_mfma_f32_16x16x32_bf16(
                    af[mf], bf[nf], acc[mf][nf], 0, 0, 0);
    };

    load_tile(0);
    for (int kb = 0; kb < K_; kb += 32) {
        __syncthreads();
        write_tile();
        __syncthreads();
        if (kb + 32 < K_) load_tile(kb + 32);
        compute();
    }
    const int lr = lane & 15;
    const int lgg = lane >> 4;
    #pragma unroll
    for (int mf = 0; mf < 4; ++mf)
        #pragma unroll
        for (int nf = 0; nf < 4; ++nf)
            #pragma unroll
            for (int j = 0; j < 4; ++j) {
                const int r = row0 + wrr * 64 + mf * 16 + lgg * 4 + j;
                const int c = col0 + wcc * 64 + nf * 16 + lr;
                C[(size_t)r * N_ + c] = acc[mf][nf][j];
            }
}

extern "C" void kernel_launch(void* const* d_in, const int* in_sizes, int n_in,
                              void* d_out, int out_size, void* d_ws, size_t ws_size,
                              hipStream_t stream) {
    const float* X  = (const float*)d_in[0];
    const int*   Q  = (const int*)d_in[1];
    const float* SZ = (const float*)d_in[2];
    float* C = (float*)d_out;

    const size_t xb_bytes = (size_t)M_ * K_ * 2;
    const size_t wb_bytes = (size_t)N_ * K_ * 2;
    if (ws_size >= xb_bytes + wb_bytes) {
        unsigned short* Xb = (unsigned short*)d_ws;
        unsigned short* Wb = (unsigned short*)((char*)d_ws + xb_bytes);
        cvt_x_kernel<<<(M_ * (K_ / 8)) / 256, 256, 0, stream>>>(X, Xb);
        deq_w_kernel<<<(N_ * (K_ / 8)) / 256, 256, 0, stream>>>(Q, SZ, Wb);
        gemm_bf16_breg<<<dim3(1376), dim3(512), 0, stream>>>(Xb, Wb, C);
    } else {
        dim3 grid(M_ / 128, N_ / 128);
        w4_gemm_fused<<<grid, dim3(256), 0, stream>>>(X, Q, SZ, C);
    }
}